// Round 1
// baseline (94.935 us; speedup 1.0000x reference)
//
#include <hip/hip_runtime.h>
#include <hip/hip_bf16.h>
#include <cstdint>

// ExemplarAttention: logits[b,c] = gamma * log( sum_{n: label[n]=c} exp(-beta * d[b,n]) + eps )
// d[b,n] = x2w[b] + e2w[n] - 2 * sum_k (x[b,k]*w[k]) * E[n,k]
//
// Strategy:
//  - prep: w = softmax(w_u)+eps, beta/gamma = softplus+eps, bf16 casts of (x*w) and E,
//          fp32 row sums x2w / e2w.
//  - GEMM (bf16 MFMA 16x16x32): A-operand = E rows (exemplars), B-operand = (x*w) rows.
//    acc fragment: exemplar = (lane>>4)*4+reg, batch = lane&15.
//  - epilogue: sim = exp(-beta*d) in fp16, class-reduce via mfma_f32_16x16x16f16 with an
//    in-register one-hot(label) B operand (no LDS atomics), then global atomicAdd into
//    class_sum (B x 10), finalize applies gamma*log.

typedef __attribute__((ext_vector_type(4))) float f32x4;
typedef __attribute__((ext_vector_type(8))) __bf16 bf16x8;
typedef __attribute__((ext_vector_type(4))) _Float16 half4;
typedef __attribute__((ext_vector_type(4))) unsigned int u32x4;

#define DDIM 512
#define NC 10
#define EPSF 1e-9f

typedef const __attribute__((address_space(1))) void* gas_ptr;
typedef __attribute__((address_space(3))) void* las_ptr;

__device__ inline void async16(const void* g, void* l) {
  __builtin_amdgcn_global_load_lds((gas_ptr)g, (las_ptr)l, 16, 0, 0);
}

__device__ inline unsigned short f2bf(float f) {
  unsigned int u = __float_as_uint(f);
  u += 0x7FFFu + ((u >> 16) & 1u);   // round-to-nearest-even
  return (unsigned short)(u >> 16);
}

__device__ inline float wave_sum(float v) {
  #pragma unroll
  for (int o = 32; o > 0; o >>= 1) v += __shfl_xor(v, o, 64);
  return v;
}

__device__ inline float softplus(float x) {
  return (x > 20.0f) ? x : log1pf(__expf(x));
}

// ---- kernel 1: w = softmax(w_u)+eps ; scal = {beta, gamma} -------------------
__global__ void prep_w(const float* __restrict__ wu, const float* __restrict__ gu,
                       const float* __restrict__ bu, float* __restrict__ w,
                       float* __restrict__ scal) {
  __shared__ float sm[16];
  int t = threadIdx.x, lane = t & 63, wd = t >> 6;
  float v = wu[t];
  float m = v;
  #pragma unroll
  for (int o = 32; o > 0; o >>= 1) m = fmaxf(m, __shfl_xor(m, o, 64));
  if (lane == 0) sm[wd] = m;
  __syncthreads();
  float mm = sm[0];
  #pragma unroll
  for (int i = 1; i < 8; ++i) mm = fmaxf(mm, sm[i]);
  float e = __expf(v - mm);
  float s = wave_sum(e);
  if (lane == 0) sm[8 + wd] = s;
  __syncthreads();
  float ss = 0.f;
  #pragma unroll
  for (int i = 0; i < 8; ++i) ss += sm[8 + i];
  w[t] = e / ss + EPSF;
  if (t == 0) {
    scal[0] = softplus(bu[0]) + EPSF;   // beta
    scal[1] = softplus(gu[0]) + EPSF;   // gamma
  }
}

// ---- kernel 2: per-row bf16 cast + weighted square sum ----------------------
// one wave per row (64 lanes x 8 elems = 512)
__global__ void prep_rows(const float* __restrict__ in, const float* __restrict__ w,
                          unsigned short* __restrict__ obf, float* __restrict__ osq,
                          int mulw) {
  int lane = threadIdx.x & 63, wd = threadIdx.x >> 6;
  size_t row = (size_t)blockIdx.x * 4 + wd;
  const float* p = in + row * DDIM + lane * 8;
  const float* pw = w + lane * 8;
  float4 va = *(const float4*)(p);
  float4 vb = *(const float4*)(p + 4);
  float4 wa = *(const float4*)(pw);
  float4 wb = *(const float4*)(pw + 4);
  float s = va.x * va.x * wa.x + va.y * va.y * wa.y + va.z * va.z * wa.z + va.w * va.w * wa.w
          + vb.x * vb.x * wb.x + vb.y * vb.y * wb.y + vb.z * vb.z * wb.z + vb.w * vb.w * wb.w;
  unsigned short o[8];
  if (mulw) {
    o[0] = f2bf(va.x * wa.x); o[1] = f2bf(va.y * wa.y);
    o[2] = f2bf(va.z * wa.z); o[3] = f2bf(va.w * wa.w);
    o[4] = f2bf(vb.x * wb.x); o[5] = f2bf(vb.y * wb.y);
    o[6] = f2bf(vb.z * wb.z); o[7] = f2bf(vb.w * wb.w);
  } else {
    o[0] = f2bf(va.x); o[1] = f2bf(va.y); o[2] = f2bf(va.z); o[3] = f2bf(va.w);
    o[4] = f2bf(vb.x); o[5] = f2bf(vb.y); o[6] = f2bf(vb.z); o[7] = f2bf(vb.w);
  }
  u32x4 pk;
  pk[0] = (unsigned)o[0] | ((unsigned)o[1] << 16);
  pk[1] = (unsigned)o[2] | ((unsigned)o[3] << 16);
  pk[2] = (unsigned)o[4] | ((unsigned)o[5] << 16);
  pk[3] = (unsigned)o[6] | ((unsigned)o[7] << 16);
  *(u32x4*)(obf + row * DDIM + lane * 8) = pk;
  s = wave_sum(s);
  if (lane == 0) osq[row] = s;
}

// ---- kernel 3: fused GEMM + exp + class reduce ------------------------------
// grid: (B/128, N/128); block 256 (4 waves, 2x2 over (exemplar, batch))
__global__ __launch_bounds__(256) void gemm_fused(
    const unsigned short* __restrict__ Ebf, const unsigned short* __restrict__ Xbf,
    const int* __restrict__ labels, const float* __restrict__ x2w,
    const float* __restrict__ e2w, const float* __restrict__ scal,
    float* __restrict__ csum) {
  __shared__ __attribute__((aligned(16))) unsigned short Es[128 * 32];
  __shared__ __attribute__((aligned(16))) unsigned short Xs[128 * 32];
  __shared__ int lab[128];
  const int tid = threadIdx.x, lane = tid & 63, wid = tid >> 6;
  const int bb = blockIdx.x;   // batch tile (0..7)
  const int be = blockIdx.y;   // exemplar tile (0..127)
  if (tid < 128) lab[tid] = labels[be * 128 + tid];

  // staging: segment s covers rows [s*16, s*16+16); lane l -> row s*16 + l/4, col (l&3)*8
  const int srow = lane >> 2, scol = (lane & 3) * 8;
  const unsigned short* gE0 = Ebf + (size_t)(be * 128 + wid * 16 + srow) * DDIM + scol;
  const unsigned short* gE1 = gE0 + (size_t)64 * DDIM;
  const unsigned short* gX0 = Xbf + (size_t)(bb * 128 + wid * 16 + srow) * DDIM + scol;
  const unsigned short* gX1 = gX0 + (size_t)64 * DDIM;
  unsigned short* lE0 = &Es[wid * 512];
  unsigned short* lE1 = &Es[(wid + 4) * 512];
  unsigned short* lX0 = &Xs[wid * 512];
  unsigned short* lX1 = &Xs[(wid + 4) * 512];

  const int waveE = (wid >> 1) * 64, waveB = (wid & 1) * 64;
  int eoff[4], xoff[4];
  #pragma unroll
  for (int f = 0; f < 4; ++f) {
    eoff[f] = ((waveE + f * 16 + (lane & 15)) * 32 + (lane >> 4) * 8) * 2;  // bytes
    xoff[f] = ((waveB + f * 16 + (lane & 15)) * 32 + (lane >> 4) * 8) * 2;
  }

  f32x4 acc[4][4] = {};
  for (int kt = 0; kt < 16; ++kt) {
    async16(gE0, lE0); async16(gE1, lE1);
    async16(gX0, lX0); async16(gX1, lX1);
    gE0 += 32; gE1 += 32; gX0 += 32; gX1 += 32;
    __syncthreads();   // drains vmcnt -> staged data visible
    bf16x8 ef[4], xf[4];
    #pragma unroll
    for (int f = 0; f < 4; ++f) {
      ef[f] = *(const bf16x8*)((const char*)Es + eoff[f]);
      xf[f] = *(const bf16x8*)((const char*)Xs + xoff[f]);
    }
    #pragma unroll
    for (int fe = 0; fe < 4; ++fe)
      #pragma unroll
      for (int fb = 0; fb < 4; ++fb)
        acc[fe][fb] = __builtin_amdgcn_mfma_f32_16x16x32_bf16(ef[fe], xf[fb], acc[fe][fb], 0, 0, 0);
    __syncthreads();
  }

  // epilogue: sim = exp(-beta*(x2w + e2w - 2*cross)); class-reduce via one-hot MFMA.
  const float beta = scal[0];
  const int rb = (lane >> 4) * 4;   // exemplar-local base in acc frags / D rows
  const int col = lane & 15;        // batch-local in acc frags; class in cs frags
  float e2v[4][4];
  #pragma unroll
  for (int fe = 0; fe < 4; ++fe)
    #pragma unroll
    for (int r = 0; r < 4; ++r)
      e2v[fe][r] = e2w[be * 128 + waveE + fe * 16 + rb + r];
  half4 oh[4];
  #pragma unroll
  for (int fe = 0; fe < 4; ++fe)
    #pragma unroll
    for (int i = 0; i < 4; ++i)
      oh[fe][i] = (lab[waveE + fe * 16 + rb + i] == col) ? (_Float16)1.0f : (_Float16)0.0f;

  #pragma unroll
  for (int fb = 0; fb < 4; ++fb) {
    const float xv = x2w[bb * 128 + waveB + fb * 16 + col];
    f32x4 cs = {0.f, 0.f, 0.f, 0.f};
    #pragma unroll
    for (int fe = 0; fe < 4; ++fe) {
      half4 sa;
      #pragma unroll
      for (int r = 0; r < 4; ++r)
        sa[r] = (_Float16)__expf(-beta * (xv + e2v[fe][r] - 2.0f * acc[fe][fb][r]));
      cs = __builtin_amdgcn_mfma_f32_16x16x16f16(sa, oh[fe], cs, 0, 0, 0);
    }
    if (col < NC) {
      const int brow = bb * 128 + waveB + fb * 16 + rb;
      #pragma unroll
      for (int r = 0; r < 4; ++r)
        atomicAdd(&csum[(size_t)(brow + r) * NC + col], cs[r]);
    }
  }
}

// ---- kernel 4: logits = gamma * log(class_sum + eps) ------------------------
__global__ void finalize(const float* __restrict__ cs, const float* __restrict__ scal,
                         float* __restrict__ out, int n) {
  int i = blockIdx.x * 256 + threadIdx.x;
  if (i < n) out[i] = scal[1] * logf(cs[i] + EPSF);
}

extern "C" void kernel_launch(void* const* d_in, const int* in_sizes, int n_in,
                              void* d_out, int out_size, void* d_ws, size_t ws_size,
                              hipStream_t stream) {
  const float* x  = (const float*)d_in[0];
  const float* ex = (const float*)d_in[1];
  const int* labels = (const int*)d_in[2];
  const float* wu = (const float*)d_in[3];
  const float* gu = (const float*)d_in[4];
  const float* bu = (const float*)d_in[5];
  float* out = (float*)d_out;
  const int B = in_sizes[0] / DDIM;   // 1024
  const int N = in_sizes[2];          // 16384

  char* ws = (char*)d_ws;
  const size_t off_scal = 0;
  const size_t off_w    = 256;
  const size_t off_x2w  = 4096;
  const size_t off_e2w  = off_x2w + (size_t)B * 4;
  const size_t off_cs   = off_e2w + (size_t)N * 4;
  const size_t off_xbf  = off_cs + (size_t)B * NC * 4;
  const size_t off_ebf  = off_xbf + (size_t)B * DDIM * 2;
  const size_t need     = off_ebf + (size_t)N * DDIM * 2;
  if (ws_size < need) return;   // insufficient scratch; fail loudly (zeros)

  float* scal = (float*)(ws + off_scal);
  float* w    = (float*)(ws + off_w);
  float* x2w  = (float*)(ws + off_x2w);
  float* e2w  = (float*)(ws + off_e2w);
  float* cs   = (float*)(ws + off_cs);
  unsigned short* xbf = (unsigned short*)(ws + off_xbf);
  unsigned short* ebf = (unsigned short*)(ws + off_ebf);

  prep_w<<<1, DDIM, 0, stream>>>(wu, gu, bu, w, scal);
  (void)hipMemsetAsync(cs, 0, (size_t)B * NC * 4, stream);
  prep_rows<<<B / 4, 256, 0, stream>>>(x, w, xbf, x2w, 1);
  prep_rows<<<N / 4, 256, 0, stream>>>(ex, w, ebf, e2w, 0);
  gemm_fused<<<dim3(B / 128, N / 128), 256, 0, stream>>>(ebf, xbf, labels, x2w, e2w, scal, cs);
  finalize<<<(B * NC + 255) / 256, 256, 0, stream>>>(cs, scal, out, B * NC);
}

// Round 2
// 89.154 us; speedup vs baseline: 1.0648x; 1.0648x over previous
//
#include <hip/hip_runtime.h>
#include <hip/hip_bf16.h>
#include <cstdint>

// ExemplarAttention: logits[b,c] = gamma * log( sum_{n: label[n]=c} exp(-beta * d[b,n]) + eps )
// d[b,n] = x2w[b] + e2w[n] - 2 * sum_k (x[b,k]*w[k]) * E[n,k]
//
// Round 2: m97-style GEMM structure.
//  - BK=64, single-buffered LDS 2x16KB, global_load_lds width-16, 8 K-iterations.
//  - XOR swizzle (chunk ^= row&7) both-sides: pre-swizzled global source + swizzled ds_read.
//  - Bijective XCD-aware block swizzle: each XCD owns 16 exemplar tiles x all batch tiles.
//  - Epilogue: sim = exp(-beta*d) in fp16, class-reduce via mfma_f32_16x16x16f16 with an
//    in-register one-hot(label) B operand, then global atomicAdd into class_sum (B x 10).

typedef __attribute__((ext_vector_type(4))) float f32x4;
typedef __attribute__((ext_vector_type(8))) __bf16 bf16x8;
typedef __attribute__((ext_vector_type(4))) _Float16 half4;
typedef __attribute__((ext_vector_type(4))) unsigned int u32x4;

#define DDIM 512
#define NC 10
#define EPSF 1e-9f

typedef const __attribute__((address_space(1))) void* gas_ptr;
typedef __attribute__((address_space(3))) void* las_ptr;

__device__ inline void async16(const void* g, void* l) {
  __builtin_amdgcn_global_load_lds((gas_ptr)g, (las_ptr)l, 16, 0, 0);
}

__device__ inline unsigned short f2bf(float f) {
  unsigned int u = __float_as_uint(f);
  u += 0x7FFFu + ((u >> 16) & 1u);   // round-to-nearest-even
  return (unsigned short)(u >> 16);
}

__device__ inline float wave_sum(float v) {
  #pragma unroll
  for (int o = 32; o > 0; o >>= 1) v += __shfl_xor(v, o, 64);
  return v;
}

__device__ inline float softplus(float x) {
  return (x > 20.0f) ? x : log1pf(__expf(x));
}

// ---- kernel 1: w = softmax(w_u)+eps ; scal = {beta, gamma} -------------------
__global__ void prep_w(const float* __restrict__ wu, const float* __restrict__ gu,
                       const float* __restrict__ bu, float* __restrict__ w,
                       float* __restrict__ scal) {
  __shared__ float sm[16];
  int t = threadIdx.x, lane = t & 63, wd = t >> 6;
  float v = wu[t];
  float m = v;
  #pragma unroll
  for (int o = 32; o > 0; o >>= 1) m = fmaxf(m, __shfl_xor(m, o, 64));
  if (lane == 0) sm[wd] = m;
  __syncthreads();
  float mm = sm[0];
  #pragma unroll
  for (int i = 1; i < 8; ++i) mm = fmaxf(mm, sm[i]);
  float e = __expf(v - mm);
  float s = wave_sum(e);
  if (lane == 0) sm[8 + wd] = s;
  __syncthreads();
  float ss = 0.f;
  #pragma unroll
  for (int i = 0; i < 8; ++i) ss += sm[8 + i];
  w[t] = e / ss + EPSF;
  if (t == 0) {
    scal[0] = softplus(bu[0]) + EPSF;   // beta
    scal[1] = softplus(gu[0]) + EPSF;   // gamma
  }
}

// ---- kernel 2: per-row bf16 cast + weighted square sum ----------------------
// one wave per row (64 lanes x 8 elems = 512)
__global__ void prep_rows(const float* __restrict__ in, const float* __restrict__ w,
                          unsigned short* __restrict__ obf, float* __restrict__ osq,
                          int mulw) {
  int lane = threadIdx.x & 63, wd = threadIdx.x >> 6;
  size_t row = (size_t)blockIdx.x * 4 + wd;
  const float* p = in + row * DDIM + lane * 8;
  const float* pw = w + lane * 8;
  float4 va = *(const float4*)(p);
  float4 vb = *(const float4*)(p + 4);
  float4 wa = *(const float4*)(pw);
  float4 wb = *(const float4*)(pw + 4);
  float s = va.x * va.x * wa.x + va.y * va.y * wa.y + va.z * va.z * wa.z + va.w * va.w * wa.w
          + vb.x * vb.x * wb.x + vb.y * vb.y * wb.y + vb.z * vb.z * wb.z + vb.w * vb.w * wb.w;
  unsigned short o[8];
  if (mulw) {
    o[0] = f2bf(va.x * wa.x); o[1] = f2bf(va.y * wa.y);
    o[2] = f2bf(va.z * wa.z); o[3] = f2bf(va.w * wa.w);
    o[4] = f2bf(vb.x * wb.x); o[5] = f2bf(vb.y * wb.y);
    o[6] = f2bf(vb.z * wb.z); o[7] = f2bf(vb.w * wb.w);
  } else {
    o[0] = f2bf(va.x); o[1] = f2bf(va.y); o[2] = f2bf(va.z); o[3] = f2bf(va.w);
    o[4] = f2bf(vb.x); o[5] = f2bf(vb.y); o[6] = f2bf(vb.z); o[7] = f2bf(vb.w);
  }
  u32x4 pk;
  pk[0] = (unsigned)o[0] | ((unsigned)o[1] << 16);
  pk[1] = (unsigned)o[2] | ((unsigned)o[3] << 16);
  pk[2] = (unsigned)o[4] | ((unsigned)o[5] << 16);
  pk[3] = (unsigned)o[6] | ((unsigned)o[7] << 16);
  *(u32x4*)(obf + row * DDIM + lane * 8) = pk;
  s = wave_sum(s);
  if (lane == 0) osq[row] = s;
}

// ---- kernel 3: fused GEMM + exp + class reduce ------------------------------
// 1D grid of (B/128)*(N/128)=1024 blocks; XCD-swizzled. 256 threads, 4 waves 2x2.
__global__ __launch_bounds__(256) void gemm_fused(
    const unsigned short* __restrict__ Ebf, const unsigned short* __restrict__ Xbf,
    const int* __restrict__ labels, const float* __restrict__ x2w,
    const float* __restrict__ e2w, const float* __restrict__ scal,
    float* __restrict__ csum) {
  __shared__ __attribute__((aligned(16))) unsigned short Es[128 * 64];  // [row][64] swizzled
  __shared__ __attribute__((aligned(16))) unsigned short Xs[128 * 64];
  __shared__ int lab[128];
  const int tid = threadIdx.x, lane = tid & 63, wid = tid >> 6;

  // XCD-aware bijective swizzle: XCD x gets exemplar tiles [x*16, x*16+16) x all 8 batch tiles.
  const int orig = blockIdx.x;          // 0..1023
  const int xcd = orig & 7;
  const int local = orig >> 3;          // 0..127
  const int be = xcd * 16 + (local >> 3);  // exemplar tile 0..127
  const int bb = local & 7;                // batch tile 0..7

  if (tid < 128) lab[tid] = labels[be * 128 + tid];

  // --- staging setup: 4 calls per tile, 256 thr x 16B = 4KB/call ---
  // chunk index i = c*256 + tid; row = i>>3, ch = i&7 (16B units within a 128B row).
  // LDS is linear (global_load_lds constraint); the SOURCE is pre-swizzled so that
  // LDS (row, ch) holds global (row, ch ^ (row&7)).
  const unsigned short* srcE[4];
  const unsigned short* srcX[4];
  unsigned short* dstE[4];
  unsigned short* dstX[4];
  #pragma unroll
  for (int c = 0; c < 4; ++c) {
    int i = c * 256 + tid;
    int row = i >> 3, ch = i & 7;
    int sch = ch ^ (row & 7);
    srcE[c] = Ebf + (size_t)(be * 128 + row) * DDIM + sch * 8;
    srcX[c] = Xbf + (size_t)(bb * 128 + row) * DDIM + sch * 8;
    dstE[c] = &Es[i * 8];
    dstX[c] = &Xs[i * 8];
  }

  const int waveE = (wid >> 1) * 64, waveB = (wid & 1) * 64;

  // --- fragment read offsets (bytes), swizzled to match staging ---
  int eoff[2][4], xoff[2][4];
  #pragma unroll
  for (int ks = 0; ks < 2; ++ks)
    #pragma unroll
    for (int f = 0; f < 4; ++f) {
      int erow = waveE + f * 16 + (lane & 15);
      int xrow = waveB + f * 16 + (lane & 15);
      int ch = ks * 4 + (lane >> 4);
      eoff[ks][f] = erow * 128 + ((ch ^ (erow & 7)) * 16);
      xoff[ks][f] = xrow * 128 + ((ch ^ (xrow & 7)) * 16);
    }

  f32x4 acc[4][4] = {};
  for (int kt = 0; kt < 8; ++kt) {
    #pragma unroll
    for (int c = 0; c < 4; ++c) async16(srcE[c], dstE[c]);
    #pragma unroll
    for (int c = 0; c < 4; ++c) async16(srcX[c], dstX[c]);
    #pragma unroll
    for (int c = 0; c < 4; ++c) { srcE[c] += 64; srcX[c] += 64; }
    __syncthreads();   // compiler drains vmcnt before barrier -> staged data visible
    #pragma unroll
    for (int ks = 0; ks < 2; ++ks) {
      bf16x8 ef[4], xf[4];
      #pragma unroll
      for (int f = 0; f < 4; ++f) {
        ef[f] = *(const bf16x8*)((const char*)Es + eoff[ks][f]);
        xf[f] = *(const bf16x8*)((const char*)Xs + xoff[ks][f]);
      }
      #pragma unroll
      for (int fe = 0; fe < 4; ++fe)
        #pragma unroll
        for (int fb = 0; fb < 4; ++fb)
          acc[fe][fb] = __builtin_amdgcn_mfma_f32_16x16x32_bf16(ef[fe], xf[fb], acc[fe][fb], 0, 0, 0);
    }
    __syncthreads();
  }

  // epilogue: sim = exp(-beta*(x2w + e2w - 2*cross)); class-reduce via one-hot MFMA.
  const float beta = scal[0];
  const int rb = (lane >> 4) * 4;   // exemplar-local base in acc frags / D rows
  const int col = lane & 15;        // batch-local in acc frags; class in cs frags
  float e2v[4][4];
  #pragma unroll
  for (int fe = 0; fe < 4; ++fe)
    #pragma unroll
    for (int r = 0; r < 4; ++r)
      e2v[fe][r] = e2w[be * 128 + waveE + fe * 16 + rb + r];
  half4 oh[4];
  #pragma unroll
  for (int fe = 0; fe < 4; ++fe)
    #pragma unroll
    for (int i = 0; i < 4; ++i)
      oh[fe][i] = (lab[waveE + fe * 16 + rb + i] == col) ? (_Float16)1.0f : (_Float16)0.0f;

  #pragma unroll
  for (int fb = 0; fb < 4; ++fb) {
    const float xv = x2w[bb * 128 + waveB + fb * 16 + col];
    f32x4 cs = {0.f, 0.f, 0.f, 0.f};
    #pragma unroll
    for (int fe = 0; fe < 4; ++fe) {
      half4 sa;
      #pragma unroll
      for (int r = 0; r < 4; ++r)
        sa[r] = (_Float16)__expf(-beta * (xv + e2v[fe][r] - 2.0f * acc[fe][fb][r]));
      cs = __builtin_amdgcn_mfma_f32_16x16x16f16(sa, oh[fe], cs, 0, 0, 0);
    }
    if (col < NC) {
      const int brow = bb * 128 + waveB + fb * 16 + rb;
      #pragma unroll
      for (int r = 0; r < 4; ++r)
        atomicAdd(&csum[(size_t)(brow + r) * NC + col], cs[r]);
    }
  }
}

// ---- kernel 4: logits = gamma * log(class_sum + eps) ------------------------
__global__ void finalize(const float* __restrict__ cs, const float* __restrict__ scal,
                         float* __restrict__ out, int n) {
  int i = blockIdx.x * 256 + threadIdx.x;
  if (i < n) out[i] = scal[1] * logf(cs[i] + EPSF);
}

extern "C" void kernel_launch(void* const* d_in, const int* in_sizes, int n_in,
                              void* d_out, int out_size, void* d_ws, size_t ws_size,
                              hipStream_t stream) {
  const float* x  = (const float*)d_in[0];
  const float* ex = (const float*)d_in[1];
  const int* labels = (const int*)d_in[2];
  const float* wu = (const float*)d_in[3];
  const float* gu = (const float*)d_in[4];
  const float* bu = (const float*)d_in[5];
  float* out = (float*)d_out;
  const int B = in_sizes[0] / DDIM;   // 1024
  const int N = in_sizes[2];          // 16384

  char* ws = (char*)d_ws;
  const size_t off_scal = 0;
  const size_t off_w    = 256;
  const size_t off_x2w  = 4096;
  const size_t off_e2w  = off_x2w + (size_t)B * 4;
  const size_t off_cs   = off_e2w + (size_t)N * 4;
  const size_t off_xbf  = off_cs + (size_t)B * NC * 4;
  const size_t off_ebf  = off_xbf + (size_t)B * DDIM * 2;
  const size_t need     = off_ebf + (size_t)N * DDIM * 2;
  if (ws_size < need) return;   // insufficient scratch; fail loudly (zeros)

  float* scal = (float*)(ws + off_scal);
  float* w    = (float*)(ws + off_w);
  float* x2w  = (float*)(ws + off_x2w);
  float* e2w  = (float*)(ws + off_e2w);
  float* cs   = (float*)(ws + off_cs);
  unsigned short* xbf = (unsigned short*)(ws + off_xbf);
  unsigned short* ebf = (unsigned short*)(ws + off_ebf);

  prep_w<<<1, DDIM, 0, stream>>>(wu, gu, bu, w, scal);
  (void)hipMemsetAsync(cs, 0, (size_t)B * NC * 4, stream);
  prep_rows<<<B / 4, 256, 0, stream>>>(x, w, xbf, x2w, 1);
  prep_rows<<<N / 4, 256, 0, stream>>>(ex, w, ebf, e2w, 0);
  gemm_fused<<<(B / 128) * (N / 128), 256, 0, stream>>>(ebf, xbf, labels, x2w, e2w, scal, cs);
  finalize<<<(B * NC + 255) / 256, 256, 0, stream>>>(cs, scal, out, B * NC);
}

// Round 4
// 47.920 us; speedup vs baseline: 1.9811x; 1.8605x over previous
//
#include <hip/hip_runtime.h>
#include <hip/hip_bf16.h>
#include <cstdint>

// ExemplarAttention: logits[b,c] = gamma * log( sum_{n: label[n]=c} exp(-beta * d[b,n]) + eps )
// d[b,n] = x2w[b] + e2w[n] - 2 * sum_k (x[b,k]*w[k]) * E[n,k]
//
// Round 4: fix round-3 wave-pair overwrite race. Waves sharing waveB but differing in
// waveE both produced partials for the same (brow, chunk, class) entry; round 2 summed
// them via atomicAdd, round 3's plain stores raced. Now: per-wave cs fragments go to a
// 16KB LDS buffer red[half][128][16] (reusing Es after the K-loop's final barrier), one
// barrier, then 256 threads sum halves and emit the block partial with float4 stores.
// No cross-block atomics anywhere.

typedef __attribute__((ext_vector_type(4))) float f32x4;
typedef __attribute__((ext_vector_type(8))) __bf16 bf16x8;
typedef __attribute__((ext_vector_type(4))) _Float16 half4;
typedef __attribute__((ext_vector_type(4))) unsigned int u32x4;

#define DDIM 512
#define NC 10
#define NCP 16     // classes padded for coalesced partial stores
#define EPSF 1e-9f

typedef const __attribute__((address_space(1))) void* gas_ptr;
typedef __attribute__((address_space(3))) void* las_ptr;

__device__ inline void async16(const void* g, void* l) {
  __builtin_amdgcn_global_load_lds((gas_ptr)g, (las_ptr)l, 16, 0, 0);
}

__device__ inline unsigned short f2bf(float f) {
  unsigned int u = __float_as_uint(f);
  u += 0x7FFFu + ((u >> 16) & 1u);   // round-to-nearest-even
  return (unsigned short)(u >> 16);
}

__device__ inline float wave_sum(float v) {
  #pragma unroll
  for (int o = 32; o > 0; o >>= 1) v += __shfl_xor(v, o, 64);
  return v;
}

__device__ inline float softplus(float x) {
  return (x > 20.0f) ? x : log1pf(__expf(x));
}

// ---- kernel 1: w = softmax(w_u)+eps ; scal = {beta, gamma} -------------------
__global__ void prep_w(const float* __restrict__ wu, const float* __restrict__ gu,
                       const float* __restrict__ bu, float* __restrict__ w,
                       float* __restrict__ scal) {
  __shared__ float sm[16];
  int t = threadIdx.x, lane = t & 63, wd = t >> 6;
  float v = wu[t];
  float m = v;
  #pragma unroll
  for (int o = 32; o > 0; o >>= 1) m = fmaxf(m, __shfl_xor(m, o, 64));
  if (lane == 0) sm[wd] = m;
  __syncthreads();
  float mm = sm[0];
  #pragma unroll
  for (int i = 1; i < 8; ++i) mm = fmaxf(mm, sm[i]);
  float e = __expf(v - mm);
  float s = wave_sum(e);
  if (lane == 0) sm[8 + wd] = s;
  __syncthreads();
  float ss = 0.f;
  #pragma unroll
  for (int i = 0; i < 8; ++i) ss += sm[8 + i];
  w[t] = e / ss + EPSF;
  if (t == 0) {
    scal[0] = softplus(bu[0]) + EPSF;   // beta
    scal[1] = softplus(gu[0]) + EPSF;   // gamma
  }
}

// ---- kernel 2: per-row bf16 cast + weighted square sum ----------------------
// one wave per row (64 lanes x 8 elems = 512)
__global__ void prep_rows(const float* __restrict__ in, const float* __restrict__ w,
                          unsigned short* __restrict__ obf, float* __restrict__ osq,
                          int mulw) {
  int lane = threadIdx.x & 63, wd = threadIdx.x >> 6;
  size_t row = (size_t)blockIdx.x * 4 + wd;
  const float* p = in + row * DDIM + lane * 8;
  const float* pw = w + lane * 8;
  float4 va = *(const float4*)(p);
  float4 vb = *(const float4*)(p + 4);
  float4 wa = *(const float4*)(pw);
  float4 wb = *(const float4*)(pw + 4);
  float s = va.x * va.x * wa.x + va.y * va.y * wa.y + va.z * va.z * wa.z + va.w * va.w * wa.w
          + vb.x * vb.x * wb.x + vb.y * vb.y * wb.y + vb.z * vb.z * wb.z + vb.w * vb.w * wb.w;
  unsigned short o[8];
  if (mulw) {
    o[0] = f2bf(va.x * wa.x); o[1] = f2bf(va.y * wa.y);
    o[2] = f2bf(va.z * wa.z); o[3] = f2bf(va.w * wa.w);
    o[4] = f2bf(vb.x * wb.x); o[5] = f2bf(vb.y * wb.y);
    o[6] = f2bf(vb.z * wb.z); o[7] = f2bf(vb.w * wb.w);
  } else {
    o[0] = f2bf(va.x); o[1] = f2bf(va.y); o[2] = f2bf(va.z); o[3] = f2bf(va.w);
    o[4] = f2bf(vb.x); o[5] = f2bf(vb.y); o[6] = f2bf(vb.z); o[7] = f2bf(vb.w);
  }
  u32x4 pk;
  pk[0] = (unsigned)o[0] | ((unsigned)o[1] << 16);
  pk[1] = (unsigned)o[2] | ((unsigned)o[3] << 16);
  pk[2] = (unsigned)o[4] | ((unsigned)o[5] << 16);
  pk[3] = (unsigned)o[6] | ((unsigned)o[7] << 16);
  *(u32x4*)(obf + row * DDIM + lane * 8) = pk;
  s = wave_sum(s);
  if (lane == 0) osq[row] = s;
}

// ---- kernel 3: fused GEMM + exp + class partial reduce ----------------------
// 1D grid of (B/128)*(N/128)=1024 blocks; XCD-swizzled. 256 threads, 4 waves 2x2.
// part layout: part[b_global][ne][NCP], b_global in [0,1024), ne chunk in [0,128).
__global__ __launch_bounds__(256) void gemm_fused(
    const unsigned short* __restrict__ Ebf, const unsigned short* __restrict__ Xbf,
    const int* __restrict__ labels, const float* __restrict__ x2w,
    const float* __restrict__ e2w, const float* __restrict__ scal,
    float* __restrict__ part) {
  __shared__ __attribute__((aligned(16))) unsigned short smem[2 * 128 * 64];  // Es | Xs, 32KB
  __shared__ int lab[128];
  unsigned short* Es = smem;
  unsigned short* Xs = smem + 128 * 64;
  const int tid = threadIdx.x, lane = tid & 63, wid = tid >> 6;

  // XCD-aware bijective swizzle: XCD x gets exemplar tiles [x*16, x*16+16) x all 8 batch tiles.
  const int orig = blockIdx.x;          // 0..1023
  const int xcd = orig & 7;
  const int local = orig >> 3;          // 0..127
  const int be = xcd * 16 + (local >> 3);  // exemplar tile 0..127
  const int bb = local & 7;                // batch tile 0..7

  if (tid < 128) lab[tid] = labels[be * 128 + tid];

  // --- staging setup: 4 calls per tile, 256 thr x 16B = 4KB/call ---
  // chunk index i = c*256 + tid; row = i>>3, ch = i&7 (16B units within a 128B row).
  // LDS is linear (global_load_lds constraint); the SOURCE is pre-swizzled so that
  // LDS (row, ch) holds global (row, ch ^ (row&7)).
  const unsigned short* srcE[4];
  const unsigned short* srcX[4];
  unsigned short* dstE[4];
  unsigned short* dstX[4];
  #pragma unroll
  for (int c = 0; c < 4; ++c) {
    int i = c * 256 + tid;
    int row = i >> 3, ch = i & 7;
    int sch = ch ^ (row & 7);
    srcE[c] = Ebf + (size_t)(be * 128 + row) * DDIM + sch * 8;
    srcX[c] = Xbf + (size_t)(bb * 128 + row) * DDIM + sch * 8;
    dstE[c] = &Es[i * 8];
    dstX[c] = &Xs[i * 8];
  }

  const int waveE = (wid >> 1) * 64, waveB = (wid & 1) * 64;

  // --- fragment read offsets (bytes), swizzled to match staging ---
  int eoff[2][4], xoff[2][4];
  #pragma unroll
  for (int ks = 0; ks < 2; ++ks)
    #pragma unroll
    for (int f = 0; f < 4; ++f) {
      int erow = waveE + f * 16 + (lane & 15);
      int xrow = waveB + f * 16 + (lane & 15);
      int ch = ks * 4 + (lane >> 4);
      eoff[ks][f] = erow * 128 + ((ch ^ (erow & 7)) * 16);
      xoff[ks][f] = xrow * 128 + ((ch ^ (xrow & 7)) * 16);
    }

  f32x4 acc[4][4] = {};
  for (int kt = 0; kt < 8; ++kt) {
    #pragma unroll
    for (int c = 0; c < 4; ++c) async16(srcE[c], dstE[c]);
    #pragma unroll
    for (int c = 0; c < 4; ++c) async16(srcX[c], dstX[c]);
    #pragma unroll
    for (int c = 0; c < 4; ++c) { srcE[c] += 64; srcX[c] += 64; }
    __syncthreads();   // compiler drains vmcnt before barrier -> staged data visible
    #pragma unroll
    for (int ks = 0; ks < 2; ++ks) {
      bf16x8 ef[4], xf[4];
      #pragma unroll
      for (int f = 0; f < 4; ++f) {
        ef[f] = *(const bf16x8*)((const char*)Es + eoff[ks][f]);
        xf[f] = *(const bf16x8*)((const char*)Xs + xoff[ks][f]);
      }
      #pragma unroll
      for (int fe = 0; fe < 4; ++fe)
        #pragma unroll
        for (int fb = 0; fb < 4; ++fb)
          acc[fe][fb] = __builtin_amdgcn_mfma_f32_16x16x32_bf16(ef[fe], xf[fb], acc[fe][fb], 0, 0, 0);
    }
    __syncthreads();   // all waves done reading Es/Xs -> safe to repurpose below
  }

  // epilogue: sim = exp(-beta*(x2w + e2w - 2*cross)); class-reduce via one-hot MFMA.
  const float beta = scal[0];
  const int rb = (lane >> 4) * 4;   // row base within 16x16 fragment
  const int col = lane & 15;        // batch-local in acc frags; class in cs frags
  float e2v[4][4];
  #pragma unroll
  for (int fe = 0; fe < 4; ++fe)
    #pragma unroll
    for (int r = 0; r < 4; ++r)
      e2v[fe][r] = e2w[be * 128 + waveE + fe * 16 + rb + r];
  half4 oh[4];
  #pragma unroll
  for (int fe = 0; fe < 4; ++fe)
    #pragma unroll
    for (int i = 0; i < 4; ++i)
      oh[fe][i] = (lab[waveE + fe * 16 + rb + i] == col) ? (_Float16)1.0f : (_Float16)0.0f;

  f32x4 csv[4];
  #pragma unroll
  for (int fb = 0; fb < 4; ++fb) {
    const float xv = x2w[bb * 128 + waveB + fb * 16 + col];
    f32x4 cs = {0.f, 0.f, 0.f, 0.f};
    #pragma unroll
    for (int fe = 0; fe < 4; ++fe) {
      half4 sa;
      #pragma unroll
      for (int r = 0; r < 4; ++r)
        sa[r] = (_Float16)__expf(-beta * (xv + e2v[fe][r] - 2.0f * acc[fe][fb][r]));
      cs = __builtin_amdgcn_mfma_f32_16x16x16f16(sa, oh[fe], cs, 0, 0, 0);
    }
    csv[fb] = cs;   // cs[r]: class-sum for batch row (waveB+fb*16+rb+r), class=col
  }

  // intra-block combine of the two exemplar halves via LDS (reuse Es region, 16KB):
  // red[half][brow_local][16] with half = waveE>>6.
  float* red = (float*)smem;
  const int half = waveE >> 6;
  #pragma unroll
  for (int fb = 0; fb < 4; ++fb)
    #pragma unroll
    for (int r = 0; r < 4; ++r)
      red[(((half << 7) | (waveB + fb * 16 + rb + r)) << 4) | col] = csv[fb][r];
  __syncthreads();

  // sum halves, store block partial (128 x 16 f32) with aligned float4 stores.
  {
    const int o = tid * 8;        // 0..2047
    const int rl = o >> 4;        // brow_local 0..127
    const int c0 = o & 15;        // 0 or 8
    const float4* p0 = (const float4*)&red[(rl << 4) | c0];
    const float4* p1 = (const float4*)&red[((128 | rl) << 4) | c0];
    float4 a0 = p0[0], a1 = p0[1], b0 = p1[0], b1 = p1[1];
    float4 r0 = {a0.x + b0.x, a0.y + b0.y, a0.z + b0.z, a0.w + b0.w};
    float4 r1 = {a1.x + b1.x, a1.y + b1.y, a1.z + b1.z, a1.w + b1.w};
    float* g = &part[(((size_t)(bb * 128 + rl)) * 128 + be) * NCP + c0];
    *(float4*)g = r0;
    *(float4*)(g + 4) = r1;
  }
}

// ---- kernel 4: logits = gamma * log( sum_ne part[b][ne][c] + eps ) ----------
// one wave per batch row; lane = ch0*16 + cl; 32 coalesced steps over chunks.
__global__ __launch_bounds__(256) void reduce_logits(
    const float* __restrict__ part, const float* __restrict__ scal,
    float* __restrict__ out) {
  const int lane = threadIdx.x & 63, wd = threadIdx.x >> 6;
  const int b = blockIdx.x * 4 + wd;
  const int cl = lane & 15, ch0 = lane >> 4;
  const float* p = part + (size_t)b * 128 * NCP;
  float v = 0.f;
  #pragma unroll
  for (int k = 0; k < 32; ++k)
    v += p[(ch0 + 4 * k) * NCP + cl];
  v += __shfl_xor(v, 16, 64);
  v += __shfl_xor(v, 32, 64);
  if (lane < NC) out[b * NC + lane] = scal[1] * logf(v + EPSF);
}

extern "C" void kernel_launch(void* const* d_in, const int* in_sizes, int n_in,
                              void* d_out, int out_size, void* d_ws, size_t ws_size,
                              hipStream_t stream) {
  const float* x  = (const float*)d_in[0];
  const float* ex = (const float*)d_in[1];
  const int* labels = (const int*)d_in[2];
  const float* wu = (const float*)d_in[3];
  const float* gu = (const float*)d_in[4];
  const float* bu = (const float*)d_in[5];
  float* out = (float*)d_out;
  const int B = in_sizes[0] / DDIM;   // 1024
  const int N = in_sizes[2];          // 16384

  char* ws = (char*)d_ws;
  const size_t off_scal = 0;
  const size_t off_w    = 256;
  const size_t off_x2w  = 4096;
  const size_t off_e2w  = off_x2w + (size_t)B * 4;
  const size_t off_xbf  = off_e2w + (size_t)N * 4;
  const size_t off_ebf  = off_xbf + (size_t)B * DDIM * 2;
  const size_t off_part = off_ebf + (size_t)N * DDIM * 2;
  const size_t need     = off_part + (size_t)B * (N / 128) * NCP * 4;
  if (ws_size < need) return;   // insufficient scratch; fail loudly (zeros)

  float* scal = (float*)(ws + off_scal);
  float* w    = (float*)(ws + off_w);
  float* x2w  = (float*)(ws + off_x2w);
  float* e2w  = (float*)(ws + off_e2w);
  unsigned short* xbf = (unsigned short*)(ws + off_xbf);
  unsigned short* ebf = (unsigned short*)(ws + off_ebf);
  float* part = (float*)(ws + off_part);

  prep_w<<<1, DDIM, 0, stream>>>(wu, gu, bu, w, scal);
  prep_rows<<<B / 4, 256, 0, stream>>>(x, w, xbf, x2w, 1);
  prep_rows<<<N / 4, 256, 0, stream>>>(ex, w, ebf, e2w, 0);
  gemm_fused<<<(B / 128) * (N / 128), 256, 0, stream>>>(ebf, xbf, labels, x2w, e2w, scal, part);
  reduce_logits<<<B / 4, 256, 0, stream>>>(part, scal, out);
}

// Round 5
// 43.463 us; speedup vs baseline: 2.1843x; 1.1025x over previous
//
#include <hip/hip_runtime.h>
#include <hip/hip_bf16.h>
#include <cstdint>

// ExemplarAttention: logits[b,c] = gamma * log( sum_{n: label[n]=c} exp(-beta * d[b,n]) + eps )
// d[b,n] = x2w[b] + e2w[n] - 2 * sum_k (x[b,k]*w[k]) * E[n,k]
//
// Round 5: 256x256 tile, BK=64, 8 waves (2 exemplar-halves x 4 batch-quarters),
// double-buffered 128KB LDS with the T3 minimum-2-phase schedule: issue next-tile
// global_load_lds BEFORE compute, one __syncthreads per K-step (drain lands loads that
// flew under the 64-MFMA compute phase). Halves L2 staging traffic vs 128^2 (268->134MB)
// and halves E-tile L3 re-fetch. Epilogue: one-hot MFMA class reduce (validated r2/r4),
// LDS combine of the 2 exemplar halves, coalesced float4 partial stores; no atomics.

typedef __attribute__((ext_vector_type(4))) float f32x4;
typedef __attribute__((ext_vector_type(8))) __bf16 bf16x8;
typedef __attribute__((ext_vector_type(4))) _Float16 half4;
typedef __attribute__((ext_vector_type(4))) unsigned int u32x4;

#define DDIM 512
#define NC 10
#define NCP 16
#define NECH 64    // exemplar chunks (16384/256)
#define EPSF 1e-9f

typedef const __attribute__((address_space(1))) void* gas_ptr;
typedef __attribute__((address_space(3))) void* las_ptr;

__device__ inline void async16(const void* g, void* l) {
  __builtin_amdgcn_global_load_lds((gas_ptr)g, (las_ptr)l, 16, 0, 0);
}

__device__ inline unsigned short f2bf(float f) {
  unsigned int u = __float_as_uint(f);
  u += 0x7FFFu + ((u >> 16) & 1u);   // round-to-nearest-even
  return (unsigned short)(u >> 16);
}

__device__ inline float wave_sum(float v) {
  #pragma unroll
  for (int o = 32; o > 0; o >>= 1) v += __shfl_xor(v, o, 64);
  return v;
}

__device__ inline float softplus(float x) {
  return (x > 20.0f) ? x : log1pf(__expf(x));
}

// ---- kernel 1: w = softmax(w_u)+eps ; scal = {beta, gamma} -------------------
__global__ void prep_w(const float* __restrict__ wu, const float* __restrict__ gu,
                       const float* __restrict__ bu, float* __restrict__ w,
                       float* __restrict__ scal) {
  __shared__ float sm[16];
  int t = threadIdx.x, lane = t & 63, wd = t >> 6;
  float v = wu[t];
  float m = v;
  #pragma unroll
  for (int o = 32; o > 0; o >>= 1) m = fmaxf(m, __shfl_xor(m, o, 64));
  if (lane == 0) sm[wd] = m;
  __syncthreads();
  float mm = sm[0];
  #pragma unroll
  for (int i = 1; i < 8; ++i) mm = fmaxf(mm, sm[i]);
  float e = __expf(v - mm);
  float s = wave_sum(e);
  if (lane == 0) sm[8 + wd] = s;
  __syncthreads();
  float ss = 0.f;
  #pragma unroll
  for (int i = 0; i < 8; ++i) ss += sm[8 + i];
  w[t] = e / ss + EPSF;
  if (t == 0) {
    scal[0] = softplus(bu[0]) + EPSF;   // beta
    scal[1] = softplus(gu[0]) + EPSF;   // gamma
  }
}

// ---- kernel 2: per-row bf16 cast + weighted square sum ----------------------
__global__ void prep_rows(const float* __restrict__ in, const float* __restrict__ w,
                          unsigned short* __restrict__ obf, float* __restrict__ osq,
                          int mulw) {
  int lane = threadIdx.x & 63, wd = threadIdx.x >> 6;
  size_t row = (size_t)blockIdx.x * 4 + wd;
  const float* p = in + row * DDIM + lane * 8;
  const float* pw = w + lane * 8;
  float4 va = *(const float4*)(p);
  float4 vb = *(const float4*)(p + 4);
  float4 wa = *(const float4*)(pw);
  float4 wb = *(const float4*)(pw + 4);
  float s = va.x * va.x * wa.x + va.y * va.y * wa.y + va.z * va.z * wa.z + va.w * va.w * wa.w
          + vb.x * vb.x * wb.x + vb.y * vb.y * wb.y + vb.z * vb.z * wb.z + vb.w * vb.w * wb.w;
  unsigned short o[8];
  if (mulw) {
    o[0] = f2bf(va.x * wa.x); o[1] = f2bf(va.y * wa.y);
    o[2] = f2bf(va.z * wa.z); o[3] = f2bf(va.w * wa.w);
    o[4] = f2bf(vb.x * wb.x); o[5] = f2bf(vb.y * wb.y);
    o[6] = f2bf(vb.z * wb.z); o[7] = f2bf(vb.w * wb.w);
  } else {
    o[0] = f2bf(va.x); o[1] = f2bf(va.y); o[2] = f2bf(va.z); o[3] = f2bf(va.w);
    o[4] = f2bf(vb.x); o[5] = f2bf(vb.y); o[6] = f2bf(vb.z); o[7] = f2bf(vb.w);
  }
  u32x4 pk;
  pk[0] = (unsigned)o[0] | ((unsigned)o[1] << 16);
  pk[1] = (unsigned)o[2] | ((unsigned)o[3] << 16);
  pk[2] = (unsigned)o[4] | ((unsigned)o[5] << 16);
  pk[3] = (unsigned)o[6] | ((unsigned)o[7] << 16);
  *(u32x4*)(obf + row * DDIM + lane * 8) = pk;
  s = wave_sum(s);
  if (lane == 0) osq[row] = s;
}

// ---- kernel 3: fused GEMM + exp + class partial reduce ----------------------
// grid: 256 blocks (64 exemplar tiles x 4 batch tiles), 512 threads = 8 waves.
// Wave (wid>>2) = exemplar half (128 rows), (wid&3) = batch quarter (64 cols).
// part layout: part[b_global][echunk][NCP], echunk in [0,64).
__global__ __launch_bounds__(512, 2) void gemm_fused(
    const unsigned short* __restrict__ Ebf, const unsigned short* __restrict__ Xbf,
    const int* __restrict__ labels, const float* __restrict__ x2w,
    const float* __restrict__ e2w, const float* __restrict__ scal,
    float* __restrict__ part) {
  // 2 buffers x (E 32KB | X 32KB) = 128KB; E block at +0, X block at +16384 shorts.
  __shared__ __attribute__((aligned(16))) unsigned short smem[2 * 2 * 16384];
  __shared__ int lab[256];
  const int tid = threadIdx.x, lane = tid & 63, wid = tid >> 6;

  // XCD-aware bijective swizzle: 256 blocks, XCD x gets E-tiles [x*8, x*8+8) x 4 b-tiles.
  const int orig = blockIdx.x;          // 0..255
  const int xcd = orig & 7;
  const int local = orig >> 3;          // 0..31
  const int be = xcd * 8 + (local >> 2);   // exemplar tile 0..63
  const int bb = local & 3;                // batch tile 0..3

  if (tid < 256) lab[tid] = labels[be * 256 + tid];

  // --- staging: 4 calls per operand per K-step, 512 thr x 16B = 8KB/call ---
  // i = c*512 + tid in [0,2048): row = i>>3 (256 rows), ch = i&7 (16B units in 128B row).
  // LDS linear; SOURCE pre-swizzled: LDS (row,ch) holds global (row, ch^(row&7)).
  const unsigned short* srcE[4];
  const unsigned short* srcX[4];
  int loff[4];
  #pragma unroll
  for (int c = 0; c < 4; ++c) {
    int i = c * 512 + tid;
    int row = i >> 3, ch = i & 7;
    int sch = ch ^ (row & 7);
    srcE[c] = Ebf + (size_t)(be * 256 + row) * DDIM + sch * 8;
    srcX[c] = Xbf + (size_t)(bb * 256 + row) * DDIM + sch * 8;
    loff[c] = i * 8;   // element offset within operand block
  }

  const int WE = (wid >> 2) * 128;   // exemplar base (0 or 128)
  const int WB = (wid & 3) * 64;     // batch base (0,64,128,192)

  // --- fragment read byte-offsets within operand block, swizzle-matched ---
  int eoff[2][8], xoff[2][4];
  #pragma unroll
  for (int ks = 0; ks < 2; ++ks) {
    int ch = ks * 4 + (lane >> 4);
    #pragma unroll
    for (int f = 0; f < 8; ++f) {
      int erow = WE + f * 16 + (lane & 15);
      eoff[ks][f] = erow * 128 + ((ch ^ (erow & 7)) * 16);
    }
    #pragma unroll
    for (int f = 0; f < 4; ++f) {
      int xrow = WB + f * 16 + (lane & 15);
      xoff[ks][f] = xrow * 128 + ((ch ^ (xrow & 7)) * 16);
    }
  }

  // prologue: stage K-tile 0 into buffer 0
  #pragma unroll
  for (int c = 0; c < 4; ++c) {
    async16(srcE[c], &smem[loff[c]]);
    async16(srcX[c], &smem[16384 + loff[c]]);
    srcE[c] += 64; srcX[c] += 64;
  }
  __syncthreads();   // drains vmcnt -> buffer 0 ready

  f32x4 acc[8][4] = {};
  int cur = 0;
  for (int kt = 0; kt < 8; ++kt) {
    if (kt < 7) {   // issue next tile into the other buffer; lands under compute
      const int nb = (cur ^ 1) * 32768;
      #pragma unroll
      for (int c = 0; c < 4; ++c) {
        async16(srcE[c], &smem[nb + loff[c]]);
        async16(srcX[c], &smem[nb + 16384 + loff[c]]);
        srcE[c] += 64; srcX[c] += 64;
      }
    }
    const char* base = (const char*)&smem[cur * 32768];
    #pragma unroll
    for (int ks = 0; ks < 2; ++ks) {
      bf16x8 ef[8], xf[4];
      #pragma unroll
      for (int f = 0; f < 8; ++f) ef[f] = *(const bf16x8*)(base + eoff[ks][f]);
      #pragma unroll
      for (int f = 0; f < 4; ++f) xf[f] = *(const bf16x8*)(base + 32768 + xoff[ks][f]);
      #pragma unroll
      for (int fe = 0; fe < 8; ++fe)
        #pragma unroll
        for (int fb = 0; fb < 4; ++fb)
          acc[fe][fb] = __builtin_amdgcn_mfma_f32_16x16x32_bf16(ef[fe], xf[fb], acc[fe][fb], 0, 0, 0);
    }
    __syncthreads();   // all reads of cur done + next-tile loads landed
    cur ^= 1;
  }

  // epilogue: sim = exp(-beta*(x2w + e2w - 2*cross)); class-reduce via one-hot MFMA.
  const float beta = scal[0];
  const int rb = (lane >> 4) * 4;   // row base within 16x16 fragment
  const int col = lane & 15;        // batch col in acc frags; class in cs frags
  float e2v[8][4];
  #pragma unroll
  for (int fe = 0; fe < 8; ++fe)
    #pragma unroll
    for (int r = 0; r < 4; ++r)
      e2v[fe][r] = e2w[be * 256 + WE + fe * 16 + rb + r];
  half4 oh[8];
  #pragma unroll
  for (int fe = 0; fe < 8; ++fe)
    #pragma unroll
    for (int i = 0; i < 4; ++i)
      oh[fe][i] = (lab[WE + fe * 16 + rb + i] == col) ? (_Float16)1.0f : (_Float16)0.0f;

  f32x4 csv[4];
  #pragma unroll
  for (int fb = 0; fb < 4; ++fb) {
    const float xv = x2w[bb * 256 + WB + fb * 16 + col];
    f32x4 cs = {0.f, 0.f, 0.f, 0.f};
    #pragma unroll
    for (int fe = 0; fe < 8; ++fe) {
      half4 sa;
      #pragma unroll
      for (int r = 0; r < 4; ++r)
        sa[r] = (_Float16)__expf(-beta * (xv + e2v[fe][r] - 2.0f * acc[fe][fb][r]));
      cs = __builtin_amdgcn_mfma_f32_16x16x16f16(sa, oh[fe], cs, 0, 0, 0);
    }
    csv[fb] = cs;   // cs[r]: class-sum for batch row (WB+fb*16+rb+r), class=col
  }

  // intra-block combine of the two exemplar halves via LDS (reuse smem, 32KB):
  // red[half][brow_local 256][16], half = WE>>7.
  float* red = (float*)smem;
  const int half = WE >> 7;
  #pragma unroll
  for (int fb = 0; fb < 4; ++fb)
    #pragma unroll
    for (int r = 0; r < 4; ++r)
      red[(((half << 8) | (WB + fb * 16 + rb + r)) << 4) | col] = csv[fb][r];
  __syncthreads();

  // sum halves, store block partial (256 x 16 f32) with aligned float4 stores.
  {
    const int o = tid * 8;        // 0..4095
    const int rl = o >> 4;        // brow_local 0..255
    const int c0 = o & 15;        // 0 or 8
    const float4* p0 = (const float4*)&red[(rl << 4) | c0];
    const float4* p1 = (const float4*)&red[((256 | rl) << 4) | c0];
    float4 a0 = p0[0], a1 = p0[1], b0 = p1[0], b1 = p1[1];
    float4 r0 = {a0.x + b0.x, a0.y + b0.y, a0.z + b0.z, a0.w + b0.w};
    float4 r1 = {a1.x + b1.x, a1.y + b1.y, a1.z + b1.z, a1.w + b1.w};
    float* g = &part[(((size_t)(bb * 256 + rl)) * NECH + be) * NCP + c0];
    *(float4*)g = r0;
    *(float4*)(g + 4) = r1;
  }
}

// ---- kernel 4: logits = gamma * log( sum_ne part[b][ne][c] + eps ) ----------
__global__ __launch_bounds__(256) void reduce_logits(
    const float* __restrict__ part, const float* __restrict__ scal,
    float* __restrict__ out) {
  const int lane = threadIdx.x & 63, wd = threadIdx.x >> 6;
  const int b = blockIdx.x * 4 + wd;
  const int cl = lane & 15, ch0 = lane >> 4;
  const float* p = part + (size_t)b * NECH * NCP;
  float v = 0.f;
  #pragma unroll
  for (int k = 0; k < 16; ++k)
    v += p[(ch0 + 4 * k) * NCP + cl];
  v += __shfl_xor(v, 16, 64);
  v += __shfl_xor(v, 32, 64);
  if (lane < NC) out[b * NC + lane] = scal[1] * logf(v + EPSF);
}

extern "C" void kernel_launch(void* const* d_in, const int* in_sizes, int n_in,
                              void* d_out, int out_size, void* d_ws, size_t ws_size,
                              hipStream_t stream) {
  const float* x  = (const float*)d_in[0];
  const float* ex = (const float*)d_in[1];
  const int* labels = (const int*)d_in[2];
  const float* wu = (const float*)d_in[3];
  const float* gu = (const float*)d_in[4];
  const float* bu = (const float*)d_in[5];
  float* out = (float*)d_out;
  const int B = in_sizes[0] / DDIM;   // 1024
  const int N = in_sizes[2];          // 16384

  char* ws = (char*)d_ws;
  const size_t off_scal = 0;
  const size_t off_w    = 256;
  const size_t off_x2w  = 4096;
  const size_t off_e2w  = off_x2w + (size_t)B * 4;
  const size_t off_xbf  = off_e2w + (size_t)N * 4;
  const size_t off_ebf  = off_xbf + (size_t)B * DDIM * 2;
  const size_t off_part = off_ebf + (size_t)N * DDIM * 2;
  const size_t need     = off_part + (size_t)B * NECH * NCP * 4;
  if (ws_size < need) return;   // insufficient scratch; fail loudly (zeros)

  float* scal = (float*)(ws + off_scal);
  float* w    = (float*)(ws + off_w);
  float* x2w  = (float*)(ws + off_x2w);
  float* e2w  = (float*)(ws + off_e2w);
  unsigned short* xbf = (unsigned short*)(ws + off_xbf);
  unsigned short* ebf = (unsigned short*)(ws + off_ebf);
  float* part = (float*)(ws + off_part);

  prep_w<<<1, DDIM, 0, stream>>>(wu, gu, bu, w, scal);
  prep_rows<<<B / 4, 256, 0, stream>>>(x, w, xbf, x2w, 1);
  prep_rows<<<N / 4, 256, 0, stream>>>(ex, w, ebf, e2w, 0);
  gemm_fused<<<(N / 256) * (B / 256), 512, 0, stream>>>(ebf, xbf, labels, x2w, e2w, scal, part);
  reduce_logits<<<B / 4, 256, 0, stream>>>(part, scal, out);
}